// Round 2
// baseline (81688.556 us; speedup 1.0000x reference)
//
#include <hip/hip_runtime.h>

// GRU decoder: B=64, T=512, IN=H=512, L=2.
// Persistent kernel, software-pipelined across layers (1 grid barrier/tick).
// grid = 256 blocks x 256 threads, launched COOPERATIVELY (guaranteed
// co-residency, 1 block/CU on 256 CUs).
//   blocks [0,128)  : cell A = layer0 @ step t      (active ticks 0..511)
//   blocks [128,256): cell B = layer1 @ step t-1    (active ticks 1..512)
// Per cell-block tile: 64 batches (lane) x 4 columns (wave).
// Hidden state double-buffered TRANSPOSED [k][b] in d_ws for coalescing.

#define NBLK 256
#define NTHR 256
#define Bsz  64
#define Tlen 512
#define Kd   512
#define Hd   512
#define KC   64          // K-chunk staged in LDS
#define LP   68          // LDS pitch (64 + 4 pad): conflict-free lane reads

__device__ __forceinline__ float sigf(float v) { return 1.0f / (1.0f + __expf(-v)); }

__device__ __forceinline__ float tanhx(float v) {
  // overflow-safe tanh via exp of negative argument
  float e = __expf(-2.0f * fabsf(v));
  float t = (1.0f - e) / (1.0f + e);
  return v < 0.0f ? -t : t;
}

// Monotonic-generation device barrier. cnt/gen zeroed by hipMemsetAsync
// before launch. Agent-scope atomics; __threadfence gives release/acquire
// (LLVM lowers agent-scope fences with the cache ops needed for cross-XCD
// visibility on gfx950).
__device__ __forceinline__ void grid_barrier(unsigned* cnt, unsigned* gen, unsigned idx) {
  __syncthreads();
  if (threadIdx.x == 0) {
    __threadfence();   // release my block's global writes
    unsigned target = idx + 1u;
    unsigned arrive = __hip_atomic_fetch_add(cnt, 1u, __ATOMIC_RELAXED, __HIP_MEMORY_SCOPE_AGENT);
    if (arrive == target * NBLK - 1u) {
      __hip_atomic_store(gen, target, __ATOMIC_RELAXED, __HIP_MEMORY_SCOPE_AGENT);
    } else {
      while (__hip_atomic_load(gen, __ATOMIC_RELAXED, __HIP_MEMORY_SCOPE_AGENT) < target) {
        __builtin_amdgcn_s_sleep(1);
      }
    }
    __threadfence();   // acquire: invalidate caches before re-reading state
  }
  __syncthreads();
}

extern "C" __global__ void __launch_bounds__(NTHR, 1)
gru_persist(const float* __restrict__ x,     // [B,T,IN]
            const float* __restrict__ eh,    // [L,B,H]
            const float* __restrict__ Wih,   // [L,3H,IN]
            const float* __restrict__ Whh,   // [L,3H,H]
            const float* __restrict__ bih,   // [L,3H]
            const float* __restrict__ bhh,   // [L,3H]
            float* __restrict__ out,         // [B,T,H] ++ [L,B,H]
            float* __restrict__ ws)
{
  __shared__ float sx[KC * LP];
  __shared__ float sh[KC * LP];

  unsigned* bar_cnt = (unsigned*)ws;        // byte 0
  unsigned* bar_gen = (unsigned*)ws + 32;   // byte 128 (separate line)
  float* h0T = ws + 64;                     // 2 buffers x [512][64]
  float* h1T = h0T + 2 * Kd * Bsz;
  float* htail = out + (size_t)Bsz * Tlen * Hd;

  const int tid  = threadIdx.x;
  const int lane = tid & 63;                            // batch index
  const int wv   = __builtin_amdgcn_readfirstlane(tid >> 6);  // wave id (SGPR)
  const int cell = blockIdx.x >> 7;                     // 0: layer0, 1: layer1
  const int cb   = blockIdx.x & 127;
  const int col  = cb * 4 + wv;                         // output column 0..511
  unsigned bar = 0;

  // ---- init: copy encoder_h into parity-1 state buffers (transposed) ----
  {
    int i = blockIdx.x * NTHR + tid;   // 0..65535 == 2*64*512
    int l = i >> 15;
    int r = i & 32767;
    int k = r >> 6;
    int b = r & 63;
    float v = eh[(size_t)(l * Bsz + b) * Hd + k];
    float* dst = (l == 0) ? h0T : h1T;
    dst[Kd * Bsz + k * Bsz + b] = v;
  }
  grid_barrier(bar_cnt, bar_gen, bar); bar++;

  // tick-invariant weight row pointers (wave-uniform -> scalar loads)
  const float* Wi = Wih + (size_t)cell * 3 * Hd * Kd;
  const float* Wh = Whh + (size_t)cell * 3 * Hd * Kd;
  const float* wi0 = Wi + (size_t)(0 * Hd + col) * Kd;
  const float* wi1 = Wi + (size_t)(1 * Hd + col) * Kd;
  const float* wi2 = Wi + (size_t)(2 * Hd + col) * Kd;
  const float* wh0 = Wh + (size_t)(0 * Hd + col) * Kd;
  const float* wh1 = Wh + (size_t)(1 * Hd + col) * Kd;
  const float* wh2 = Wh + (size_t)(2 * Hd + col) * Kd;
  const float bi0 = bih[cell * 1536 + 0 * Hd + col];
  const float bi1 = bih[cell * 1536 + 1 * Hd + col];
  const float bi2 = bih[cell * 1536 + 2 * Hd + col];
  const float bh0 = bhh[cell * 1536 + 0 * Hd + col];
  const float bh1 = bhh[cell * 1536 + 1 * Hd + col];
  const float bh2 = bhh[cell * 1536 + 2 * Hd + col];

  for (int t = 0; t <= Tlen; ++t) {
    const bool active = (cell == 0) ? (t < Tlen) : (t >= 1);
    if (active) {
      const int s = (cell == 0) ? t : (t - 1);
      const float* hprevT = (cell == 0 ? h0T : h1T) + ((s + 1) & 1) * Kd * Bsz;
      float*       houtT  = (cell == 0 ? h0T : h1T) + (s & 1) * Kd * Bsz;
      const float* inT    = h0T + (s & 1) * Kd * Bsz;   // cell B only

      float ai0 = 0.f, ai1 = 0.f, ai2 = 0.f;
      float ah0 = 0.f, ah1 = 0.f, ah2 = 0.f;
      float hkeep = 0.f;

      for (int kc = 0; kc < Kd; kc += KC) {
        __syncthreads();  // protect LDS from previous chunk's readers
        if (cell == 0) {
          // stage+transpose x[b][t][kc..kc+64) -> sx[k][b]
          for (int i = tid; i < Bsz * (KC / 4); i += NTHR) {   // 1024 float4
            int b  = i >> 4;
            int k4 = (i & 15) * 4;
            const float4 v = *(const float4*)(x + ((size_t)(b * Tlen + t)) * Kd + kc + k4);
            sx[(k4 + 0) * LP + b] = v.x;
            sx[(k4 + 1) * LP + b] = v.y;
            sx[(k4 + 2) * LP + b] = v.z;
            sx[(k4 + 3) * LP + b] = v.w;
          }
        } else {
          // input already transposed: straight copy
          for (int i = tid; i < KC * (Bsz / 4); i += NTHR) {
            int k  = i >> 4;
            int b4 = (i & 15) * 4;
            *(float4*)(&sx[k * LP + b4]) = *(const float4*)(inT + (size_t)(kc + k) * Bsz + b4);
          }
        }
        // stage hprev (transposed source for both cells)
        for (int i = tid; i < KC * (Bsz / 4); i += NTHR) {
          int k  = i >> 4;
          int b4 = (i & 15) * 4;
          *(float4*)(&sh[k * LP + b4]) = *(const float4*)(hprevT + (size_t)(kc + k) * Bsz + b4);
        }
        __syncthreads();

        if (col >= kc && col < kc + KC)           // wave-uniform branch
          hkeep = sh[(col - kc) * LP + lane];     // hprev[b][col]

        #pragma unroll 8
        for (int k = 0; k < KC; ++k) {
          const int kg = kc + k;
          float xv = sx[k * LP + lane];
          float hv = sh[k * LP + lane];
          ai0 = fmaf(xv, wi0[kg], ai0);
          ai1 = fmaf(xv, wi1[kg], ai1);
          ai2 = fmaf(xv, wi2[kg], ai2);
          ah0 = fmaf(hv, wh0[kg], ah0);
          ah1 = fmaf(hv, wh1[kg], ah1);
          ah2 = fmaf(hv, wh2[kg], ah2);
        }
      }

      // fused GRU epilogue (torch.nn.GRUCell math)
      float r = sigf(ai0 + bi0 + ah0 + bh0);
      float z = sigf(ai1 + bi1 + ah1 + bh1);
      float n = tanhx(ai2 + bi2 + r * (ah2 + bh2));
      float hnew = (1.0f - z) * n + z * hkeep;

      houtT[col * Bsz + lane] = hnew;                                // coalesced
      if (cell == 1)
        out[((size_t)(lane * Tlen + s)) * Hd + col] = hnew;          // [B,T,H]
    }
    grid_barrier(bar_cnt, bar_gen, bar); bar++;
  }

  // ---- final hidden states: htail[l][b][c] = hT_l[parity1][c][b] ----
  {
    int i = blockIdx.x * NTHR + tid;   // 0..65535
    int l = i >> 15;
    int r = i & 32767;
    int b = r >> 9;
    int c = r & 511;
    const float* src = (l == 0) ? h0T : h1T;
    htail[i] = src[Kd * Bsz + c * Bsz + b];
  }
}

extern "C" void kernel_launch(void* const* d_in, const int* in_sizes, int n_in,
                              void* d_out, int out_size, void* d_ws, size_t ws_size,
                              hipStream_t stream) {
  (void)in_sizes; (void)n_in; (void)out_size; (void)ws_size;
  const float* x   = (const float*)d_in[0];
  const float* eh  = (const float*)d_in[1];
  const float* Wih = (const float*)d_in[2];
  const float* Whh = (const float*)d_in[3];
  const float* bih = (const float*)d_in[4];
  const float* bhh = (const float*)d_in[5];
  float* out = (float*)d_out;
  float* ws  = (float*)d_ws;

  // zero the barrier counters (ws is re-poisoned to 0xAA before every launch)
  hipMemsetAsync(d_ws, 0, 256, stream);

  // Cooperative launch: guarantees all 256 blocks co-resident (1 block/CU,
  // 35 KB LDS, 4 waves — far below any per-CU limit), which the persistent
  // grid barrier requires. Harness supports cooperative launch under graph
  // capture.
  void* args[] = {(void*)&x, (void*)&eh, (void*)&Wih, (void*)&Whh,
                  (void*)&bih, (void*)&bhh, (void*)&out, (void*)&ws};
  hipLaunchCooperativeKernel((const void*)gru_persist, dim3(NBLK), dim3(NTHR),
                             args, 0, stream);
}

// Round 3
// 19817.513 us; speedup vs baseline: 4.1220x; 4.1220x over previous
//
#include <hip/hip_runtime.h>

// GRU decoder B=64,T=512,IN=H=512,L=2. Persistent pipelined grid:
//   blocks [0,128)  = cell A (layer0 @ t),  blocks [128,256) = cell B (layer1 @ t-1)
// 256 blocks x 512 threads (8 waves/CU, 2/SIMD). Block = 4 cols; wave = 4 cols x K-octant.
// h-state in d_ws, [k][b] layout, written with sc0sc1 (write-through to L3 = coherence
// point), read with normal cached loads after a per-tick acquire fence (buffer_inv).
// Barrier: per-block monotonic slots (no atomic RMW contention); wave0 polls+min-reduces.

#define NBLK 256
#define NTHR 512
#define Bsz  64
#define Tlen 512
#define Kd   512
#define Hd   512
#define KC   64
#define LP   67   // LDS pitch: scalar transpose writes land 2-way max (free)

__device__ __forceinline__ float sigf(float v){ return 1.0f/(1.0f+__expf(-v)); }
__device__ __forceinline__ float tanhx(float v){
  float e=__expf(-2.0f*fabsf(v)); float t=(1.0f-e)/(1.0f+e); return v<0.0f?-t:t;
}
__device__ __forceinline__ unsigned umin2(unsigned a, unsigned b){ return a<b?a:b; }

// coherent (L2-bypassing, L3-committed) store/load
__device__ __forceinline__ void st_coh(float* p, float v){
  asm volatile("global_store_dword %0, %1, off sc0 sc1" :: "v"(p), "v"(v) : "memory");
}
__device__ __forceinline__ void st_coh_u(unsigned* p, unsigned v){
  asm volatile("global_store_dword %0, %1, off sc0 sc1" :: "v"(p), "v"(v) : "memory");
}
__device__ __forceinline__ void wait_vm0(){ asm volatile("s_waitcnt vmcnt(0)" ::: "memory"); }

// Grid barrier: release = (sc0sc1 data stores) + vmcnt(0) + slot store.
// acquire = poll slots via coherent loads, then agent acquire fence (inv L1/L2)
// so subsequent NORMAL loads see fresh h. Weights live in scalar K$ (untouched).
__device__ __forceinline__ void grid_barrier(unsigned* slots, unsigned target, int tid){
  wait_vm0();                 // every wave: my coherent stores are committed at L3
  __syncthreads();            // whole block done storing
  if(tid == 0) st_coh_u(slots + blockIdx.x, target);
  if(tid < 64){
    const unsigned* p0 = slots + tid;
    for(;;){
      unsigned a,b,c,d;
      asm volatile(
        "global_load_dword %0, %4, off sc0 sc1\n\t"
        "global_load_dword %1, %5, off sc0 sc1\n\t"
        "global_load_dword %2, %6, off sc0 sc1\n\t"
        "global_load_dword %3, %7, off sc0 sc1\n\t"
        "s_waitcnt vmcnt(0)"
        : "=v"(a),"=v"(b),"=v"(c),"=v"(d)
        : "v"(p0), "v"(p0+64), "v"(p0+128), "v"(p0+192)
        : "memory");
      unsigned m = umin2(umin2(a,b), umin2(c,d));
      #pragma unroll
      for(int off=32; off; off>>=1)
        m = umin2(m, (unsigned)__shfl_xor((int)m, off, 64));
      if(m >= target) break;
      __builtin_amdgcn_s_sleep(1);
    }
  }
  __syncthreads();
  __builtin_amdgcn_fence(__ATOMIC_ACQUIRE, "agent");  // inv vL1+L2 -> normal loads fresh
}

// stage+transpose chunk ch of x[b][t][.] into sbuf[k_local][b], pitch LP
__device__ __forceinline__ void stageA(float* sbuf, const float* __restrict__ x,
                                       int t, int ch, int tid){
  #pragma unroll
  for(int it=0; it<2; ++it){
    int q  = it*NTHR + tid;          // 0..1023
    int b  = q >> 4;
    int k4 = (q & 15) << 2;
    const float4 v = *(const float4*)(x + ((size_t)b*Tlen + t)*Kd + ch*KC + k4);
    sbuf[(k4+0)*LP + b] = v.x;
    sbuf[(k4+1)*LP + b] = v.y;
    sbuf[(k4+2)*LP + b] = v.z;
    sbuf[(k4+3)*LP + b] = v.w;
  }
}

extern "C" __global__ void __launch_bounds__(NTHR, 2)
gru_persist(const float* __restrict__ x,     // [B,T,IN]
            const float* __restrict__ eh,    // [L,B,H]
            const float* __restrict__ Wih,   // [L,3H,IN]
            const float* __restrict__ Whh,   // [L,3H,H]
            const float* __restrict__ bih,   // [L,3H]
            const float* __restrict__ bhh,   // [L,3H]
            float* __restrict__ out,         // [B,T,H] ++ [L,B,H]
            float* __restrict__ ws)
{
  __shared__ float smem[2*KC*LP];   // A: x staging dbuf; reused as reduction buffer

  unsigned* slots = (unsigned*)ws;            // 256 monotonic tick slots
  float* h0T = ws + 256;                      // 2 bufs x [512][64]
  float* h1T = h0T + 2*Kd*Bsz;
  float* htail = out + (size_t)Bsz*Tlen*Hd;

  const int tid  = threadIdx.x;
  const int lane = tid & 63;                                   // batch
  const int wv   = __builtin_amdgcn_readfirstlane(tid >> 6);   // wave id 0..7
  const int cell = blockIdx.x >> 7;                            // 0=layer0, 1=layer1
  const int cb   = blockIdx.x & 127;
  const int col0 = cb * 4;                                     // block's 4 cols
  unsigned bar = 1;

  // ---- init: encoder_h -> parity-1 state bufs, transposed [k][b], coherent ----
  {
    int i = blockIdx.x*NTHR + tid;            // 131072 threads, 65536 items
    if(i < 2*Kd*Bsz){
      int l = i >> 15, k = (i >> 6) & 511, b = i & 63;
      float v = eh[(size_t)(l*Bsz + b)*Hd + k];
      st_coh((l ? h1T : h0T) + Kd*Bsz + k*Bsz + b, v);
    }
  }
  grid_barrier(slots, bar, tid); bar++;

  // weight bases: weight(gate g, col c, k) = W?B[g*Hd*Kd + c*Kd + k]  (wave-uniform)
  const float* WiB = Wih + (size_t)cell*3*Hd*Kd + (size_t)col0*Kd;
  const float* WhB = Whh + (size_t)cell*3*Hd*Kd + (size_t)col0*Kd;
  // epilogue biases for this wave's col (clamped for waves 4..7; unused there)
  const int ec = wv & 3;
  const int ecol = col0 + ec;
  const float bi0 = bih[cell*1536 + 0*Hd + ecol] + bhh[cell*1536 + 0*Hd + ecol];
  const float bi1 = bih[cell*1536 + 1*Hd + ecol] + bhh[cell*1536 + 1*Hd + ecol];
  const float bi2 = bih[cell*1536 + 2*Hd + ecol];
  const float bh2 = bhh[cell*1536 + 2*Hd + ecol];

  for(int t = 0; t <= Tlen; ++t){
    const bool active = (cell == 0) ? (t < Tlen) : (t >= 1);
    if(active){
      const int s = (cell == 0) ? t : (t - 1);
      float* hbase = (cell == 0) ? h0T : h1T;
      const float* hprev = hbase + ((s+1)&1)*Kd*Bsz;
      float*       hout  = hbase + (s&1)*Kd*Bsz;
      const float* inT   = h0T + (s&1)*Kd*Bsz;      // cell B input (just written by A)

      float pr[4]={0,0,0,0}, pz[4]={0,0,0,0}, pni[4]={0,0,0,0}, pnh[4]={0,0,0,0};

      if(cell == 0){
        // x via LDS transpose (chunked, double-buffered); h direct global (cached)
        stageA(smem, x, t, 0, tid);
        __syncthreads();
        for(int ch = 0; ch < 8; ++ch){
          const float* cur = smem + (ch&1)*(KC*LP);
          if(ch < 7) stageA(smem + ((ch+1)&1)*(KC*LP), x, t, ch+1, tid);
          #pragma unroll
          for(int j = 0; j < 8; ++j){
            const int kl = (wv<<3) + j;          // wave's interleaved sub-slice
            const int kg = (ch<<6) + kl;
            const float xv = cur[kl*LP + lane];
            const float hv = hprev[kg*Bsz + lane];
            #pragma unroll
            for(int c = 0; c < 4; ++c){
              pr[c]  = fmaf(xv, WiB[(size_t)c*Kd + kg], pr[c]);
              pz[c]  = fmaf(xv, WiB[(size_t)Hd*Kd + c*Kd + kg], pz[c]);
              pni[c] = fmaf(xv, WiB[(size_t)2*Hd*Kd + c*Kd + kg], pni[c]);
              pr[c]  = fmaf(hv, WhB[(size_t)c*Kd + kg], pr[c]);
              pz[c]  = fmaf(hv, WhB[(size_t)Hd*Kd + c*Kd + kg], pz[c]);
              pnh[c] = fmaf(hv, WhB[(size_t)2*Hd*Kd + c*Kd + kg], pnh[c]);
            }
          }
          __syncthreads();
        }
      } else {
        // both act streams direct from [k][b] global (coalesced, L2-cached)
        #pragma unroll 8
        for(int j = 0; j < 64; ++j){
          const int kg = (wv<<6) + j;            // contiguous K-octant
          const float xv = inT[kg*Bsz + lane];
          const float hv = hprev[kg*Bsz + lane];
          #pragma unroll
          for(int c = 0; c < 4; ++c){
            pr[c]  = fmaf(xv, WiB[(size_t)c*Kd + kg], pr[c]);
            pz[c]  = fmaf(xv, WiB[(size_t)Hd*Kd + c*Kd + kg], pz[c]);
            pni[c] = fmaf(xv, WiB[(size_t)2*Hd*Kd + c*Kd + kg], pni[c]);
            pr[c]  = fmaf(hv, WhB[(size_t)c*Kd + kg], pr[c]);
            pz[c]  = fmaf(hv, WhB[(size_t)Hd*Kd + c*Kd + kg], pz[c]);
            pnh[c] = fmaf(hv, WhB[(size_t)2*Hd*Kd + c*Kd + kg], pnh[c]);
          }
        }
        __syncthreads();   // match A's pre-reduction state (smem free)
      }

      // ---- ksplit-8 reduction via LDS (aliases smem; guarded by syncs) ----
      float* red = smem;   // [(c*4+p)*8 + w][64]
      #pragma unroll
      for(int c = 0; c < 4; ++c){
        red[(((c<<2)+0)*8 + wv)*64 + lane] = pr[c];
        red[(((c<<2)+1)*8 + wv)*64 + lane] = pz[c];
        red[(((c<<2)+2)*8 + wv)*64 + lane] = pni[c];
        red[(((c<<2)+3)*8 + wv)*64 + lane] = pnh[c];
      }
      __syncthreads();
      if(wv < 4){
        const int c = wv;
        float spr=0.f, spz=0.f, spni=0.f, spnh=0.f;
        #pragma unroll
        for(int w = 0; w < 8; ++w){
          spr  += red[(((c<<2)+0)*8 + w)*64 + lane];
          spz  += red[(((c<<2)+1)*8 + w)*64 + lane];
          spni += red[(((c<<2)+2)*8 + w)*64 + lane];
          spnh += red[(((c<<2)+3)*8 + w)*64 + lane];
        }
        const int col = col0 + c;
        const float hkeep = hprev[col*Bsz + lane];
        const float r = sigf(spr + bi0);
        const float z = sigf(spz + bi1);
        const float n = tanhx(spni + bi2 + r*(spnh + bh2));
        const float hnew = (1.0f - z)*n + z*hkeep;
        st_coh(hout + col*Bsz + lane, hnew);                       // coherent, 256B/wave
        if(cell == 1)
          out[((size_t)lane*Tlen + s)*Hd + col] = hnew;            // normal store
      }
    }
    grid_barrier(slots, bar, tid); bar++;
  }

  // ---- tail: htail[l][b][c] from parity-1 bufs (post-fence normal loads) ----
  {
    int i = blockIdx.x*NTHR + tid;
    if(i < 2*Kd*Bsz){
      int l = i >> 15, b = (i >> 9) & 63, c = i & 511;
      const float* src = (l ? h1T : h0T) + Kd*Bsz;
      htail[i] = src[c*Bsz + b];
    }
  }
}

extern "C" void kernel_launch(void* const* d_in, const int* in_sizes, int n_in,
                              void* d_out, int out_size, void* d_ws, size_t ws_size,
                              hipStream_t stream) {
  (void)in_sizes; (void)n_in; (void)out_size; (void)ws_size;
  const float* x   = (const float*)d_in[0];
  const float* eh  = (const float*)d_in[1];
  const float* Wih = (const float*)d_in[2];
  const float* Whh = (const float*)d_in[3];
  const float* bih = (const float*)d_in[4];
  const float* bhh = (const float*)d_in[5];
  float* out = (float*)d_out;
  float* ws  = (float*)d_ws;

  hipMemsetAsync(d_ws, 0, 1024, stream);   // zero barrier slots

  void* args[] = {(void*)&x, (void*)&eh, (void*)&Wih, (void*)&Whh,
                  (void*)&bih, (void*)&bhh, (void*)&out, (void*)&ws};
  hipLaunchCooperativeKernel((const void*)gru_persist, dim3(NBLK), dim3(NTHR),
                             args, 0, stream);
}